// Round 11
// baseline (241.506 us; speedup 1.0000x reference)
//
#include <hip/hip_runtime.h>
#include <hip/hip_bf16.h>
#include <math.h>

typedef float f2 __attribute__((ext_vector_type(2)));
typedef float f2u __attribute__((ext_vector_type(2), aligned(4)));
typedef float f4 __attribute__((ext_vector_type(4)));
typedef short s8v __attribute__((ext_vector_type(8)));   // 8 bf16 = 4 VGPRs (MFMA frag)
typedef unsigned int u4 __attribute__((ext_vector_type(4)));

#define BN 8
#define CIN 3
#define HH 512
#define WW 512
#define KK 9
#define PATCH 27

// ws layout:
//  [0, 2048) bytes: A-fragments, bf16. For ct in {0,1}, lane L in 0..63, j in 0..7:
//    ushort at (ct*64+L)*8 + j = bf16( A[m][k] ), m = ct*16 + (L&15), k = (L>>4)*8 + j
//    A[m][k] = (m<27) ? (k<27 ? w_off[m*27+k] : (k==27 ? b_off[m] : 0)) : 0
//  [2048, 2624) bytes: 144 floats: tap k block of 16: r<12: c=r>>2,o=r&3 ->
//    o<3 ? w_def[o*27 + c*9 + k] : 0 ; r>=12: 0
__global__ void reorder_weights(const float* __restrict__ w_off,
                                const float* __restrict__ b_off,
                                const float* __restrict__ w_def,
                                void* __restrict__ ws)
{
    unsigned short* wsA = (unsigned short*)ws;
    float* wsf = (float*)((char*)ws + 2048);
    const int tid = threadIdx.x;
    for (int idx = tid; idx < 1024; idx += blockDim.x) {
        const int ct = idx >> 9;
        const int L  = (idx >> 3) & 63;
        const int j  = idx & 7;
        const int m = ct * 16 + (L & 15);
        const int k = (L >> 4) * 8 + j;
        float v = 0.0f;
        if (m < PATCH) {
            if (k < PATCH)       v = w_off[m * PATCH + k];
            else if (k == PATCH) v = b_off[m];
        }
        __hip_bfloat16 hv = __float2bfloat16(v);
        wsA[idx] = *(unsigned short*)&hv;
    }
    for (int idx = tid; idx < 144; idx += blockDim.x) {
        const int k = idx / 16, r = idx % 16;
        float v = 0.0f;
        if (r < 12) {
            const int c = r >> 2, o = r & 3;
            if (o < 3) v = w_def[o * PATCH + c * KK + k];
        }
        wsf[idx] = v;
    }
}

__global__ __launch_bounds__(256) void deform_fused_kernel(
    const float* __restrict__ x,
    const void* __restrict__ ws,
    const float* __restrict__ b_def,
    float* __restrict__ out)
{
    // per-wave scratch: patch bf16 at px*72 (4608 B) reused as fp32 ow at px*144 (9216 B)
    __shared__ __attribute__((aligned(16))) char smem[4][9216];
    const int tid = threadIdx.x;
    const int lane = tid & 63;
    char* base = smem[tid >> 6];

    const int w = blockIdx.x * blockDim.x + tid;
    const int h = blockIdx.y;
    const int b = blockIdx.z;

    const size_t plane = (size_t)HH * WW;
    const float* xb = x + (size_t)b * CIN * plane;

    // ---- 3x3x3 zero-padded patch, flat k = c*9 + t; k=27 -> 1.0 (bias input) ----
    float pf[28];
    pf[27] = 1.0f;
    #pragma unroll
    for (int c = 0; c < CIN; ++c) {
        const float* xp = xb + c * plane;
        #pragma unroll
        for (int t = 0; t < KK; ++t) {
            const int yy = h + t / 3 - 1;
            const int xx = w + t % 3 - 1;
            const bool in = ((unsigned)yy < HH) & ((unsigned)xx < WW);
            const int yc = min(max(yy, 0), HH - 1);
            const int xc = min(max(xx, 0), WW - 1);
            pf[c * KK + t] = in ? xp[yc * WW + xc] : 0.0f;
        }
    }

    // ---- pack patch -> bf16 pairs, write px-major to LDS (72 B stride) ----
    unsigned u[16];
    #pragma unroll
    for (int pr = 0; pr < 14; ++pr) {
        union { __hip_bfloat162 h2; unsigned uu; } cv;
        cv.h2 = __float22bfloat162_rn(make_float2(pf[2 * pr], pf[2 * pr + 1]));
        u[pr] = cv.uu;
    }
    u[14] = 0u; u[15] = 0u;
    #pragma unroll
    for (int j = 0; j < 4; ++j) {
        u4 q = { u[4 * j], u[4 * j + 1], u[4 * j + 2], u[4 * j + 3] };
        *(u4*)(base + lane * 72 + j * 16) = q;
    }
    asm volatile("s_waitcnt lgkmcnt(0)" ::: "memory");

    // ---- A fragments (weights, global, coalesced) ----
    const s8v* wsA = (const s8v*)ws;
    const s8v a0 = wsA[lane];        // ch rows 0..15
    const s8v a1 = wsA[64 + lane];   // ch rows 16..31

    // ---- B fragments: B[k][n], n = lane&15 (pixel in tile), k = quad*8+j ----
    const int colp = lane & 15;
    const int quad = lane >> 4;
    s8v bfr[4];
    #pragma unroll
    for (int T = 0; T < 4; ++T)
        bfr[T] = *(const s8v*)(base + (T * 16 + colp) * 72 + quad * 16);

    __builtin_amdgcn_sched_barrier(0);   // keep C-writes below B-reads (region reuse)

    // ---- 8 MFMAs; scatter C (col=px, row=ch) to fp32 LDS at px*144 ----
    const f4 zz = { 0.0f, 0.0f, 0.0f, 0.0f };
    #pragma unroll
    for (int T = 0; T < 4; ++T) {
        f4 c0 = __builtin_amdgcn_mfma_f32_16x16x32_bf16(a0, bfr[T], zz, 0, 0, 0);
        f4 c1 = __builtin_amdgcn_mfma_f32_16x16x32_bf16(a1, bfr[T], zz, 0, 0, 0);
        char* prow = base + (T * 16 + colp) * 144;
        *(f4*)(prow + (quad * 4) * 4)        = c0;   // ch quad*4 .. +3
        *(f4*)(prow + (16 + quad * 4) * 4)   = c1;   // ch 16+quad*4 .. +3
    }
    asm volatile("s_waitcnt lgkmcnt(0)" ::: "memory");

    // ---- read back own pixel's 28 conv outputs as 14 pairs ----
    f2 ow[14];
    #pragma unroll
    for (int q = 0; q < 7; ++q) {
        const f4 v = *(const f4*)(base + lane * 144 + q * 16);
        ow[2 * q]     = (f2){ v.x, v.y };
        ow[2 * q + 1] = (f2){ v.z, v.w };
    }

    const float* wsf = (const float*)((const char*)ws + 2048);

    f2 acc01 = { b_def[0], b_def[1] };
    float acc2 = b_def[2];

    // ---- 9 taps, fully unrolled, branch-free unified sampling (R10-verified) ----
    #pragma unroll
    for (int k = 0; k < KK; ++k) {
        const float* blk = wsf + k * 16;   // uniform -> s_load

        const float oy = ow[k].x;
        const float ox = ow[k].y;
        const float om = (k < 8) ? ((k & 1) ? ow[9 + (k >> 1)].y
                                            : ow[9 + (k >> 1)].x)
                                 : ow[13].x;

        const float m = __builtin_amdgcn_rcpf(1.0f + __expf(-om));

        const float py = (float)h + (float)(k / 3 - 1) + oy;
        const float px = (float)w + (float)(k % 3 - 1) + ox;
        const float y0f = floorf(py);
        const float x0f = floorf(px);
        const float dy = py - y0f;
        const float dx = px - x0f;
        const int y0 = (int)y0f;
        const int x0 = (int)x0f;

        // x side: load pair at xL, remap weights onto loaded elements
        const int xL = min(max(x0, 0), WW - 2);
        const float w0p = 1.0f - dx;
        const float w1p = dx;
        const bool P = (x0 == xL);
        const bool Q = (x0 + 1 == xL);
        const bool R = (x0 - 1 == xL);
        const float wa = P ? w0p : (Q ? w1p : 0.0f);
        const float wb = P ? w1p : (R ? w0p : 0.0f);

        // y side: clamp rows, fold validity and mask m into row weights
        const int yc0 = min(max(y0, 0), HH - 1);
        const int yc1 = min(max(y0 + 1, 0), HH - 1);
        const float ady = ((unsigned)y0 < HH)       ? (1.0f - dy) * m : 0.0f;
        const float bdy = ((unsigned)(y0 + 1) < HH) ? dy * m          : 0.0f;

        const f2 wxp = { wa, wb };
        const f2 wTe = wxp * ady;
        const f2 wBe = wxp * bdy;

        const int off0 = yc0 * WW + xL;
        const int off1 = yc1 * WW + xL;

        #pragma unroll
        for (int c = 0; c < CIN; ++c) {
            const float* xp = xb + c * plane;
            const f2 vT = *(const f2u*)(xp + off0);
            const f2 vB = *(const f2u*)(xp + off1);
            f2 s = vT * wTe;
            s = __builtin_elementwise_fma(vB, wBe, s);
            const float val = s.x + s.y;
            const f4 wq = *(const f4*)(blk + 4 * c);   // (wd0, wd1, wd2, 0)
            const f2 w01 = { wq.x, wq.y };
            const f2 vv = { val, val };
            acc01 = __builtin_elementwise_fma(w01, vv, acc01);
            acc2 = fmaf(wq.z, val, acc2);
        }
    }

    const size_t obase = (size_t)b * (CIN * plane) + (size_t)h * WW + w;
    out[obase]             = acc01.x;
    out[obase + plane]     = acc01.y;
    out[obase + 2 * plane] = acc2;
}

extern "C" void kernel_launch(void* const* d_in, const int* in_sizes, int n_in,
                              void* d_out, int out_size, void* d_ws, size_t ws_size,
                              hipStream_t stream) {
    const float* x     = (const float*)d_in[0];
    const float* w_off = (const float*)d_in[1];
    const float* b_off = (const float*)d_in[2];
    const float* w_def = (const float*)d_in[3];
    const float* b_def = (const float*)d_in[4];
    float* out = (float*)d_out;

    reorder_weights<<<1, 256, 0, stream>>>(w_off, b_off, w_def, d_ws);

    dim3 block(256, 1, 1);
    dim3 grid(WW / 256, HH, BN);  // (2, 512, 8)
    deform_fused_kernel<<<grid, block, 0, stream>>>(x, d_ws, b_def, out);
}

// Round 12
// 184.949 us; speedup vs baseline: 1.3058x; 1.3058x over previous
//
#include <hip/hip_runtime.h>
#include <math.h>

typedef float f2 __attribute__((ext_vector_type(2)));
typedef float f2u __attribute__((ext_vector_type(2), aligned(4)));
typedef float f4 __attribute__((ext_vector_type(4)));

#define BN 8
#define CIN 3
#define HH 512
#define WW 512
#define KK 9
#define PATCH 27
#define TAPBLK 112 // 56 (wy,wx) pairs | 28 wm | 12 contraction | 4 bias | 12 pad

// ws layout, tap k block of 112 floats (base 64B-aligned: 112*4=448B):
//  r in [0,56):   pair q=r>>1, half=r&1 -> w_off[(2k+half)*27+q], q>=27 -> 0
//  r in [56,84):  i=r-56 -> w_off[(18+k)*27+i], i>=27 -> 0
//  r in [84,96):  j=r-84, c=j>>2, o=j&3 -> o<3 ? w_def[o*27 + c*9 + k] : 0
//  r in [96,100): (b_off[2k], b_off[2k+1], b_off[18+k], 0)
//  r in [100,112): 0 pad
__global__ void reorder_weights(const float* __restrict__ w_off,
                                const float* __restrict__ b_off,
                                const float* __restrict__ w_def,
                                float* __restrict__ ws)
{
    for (int idx = threadIdx.x; idx < KK * TAPBLK; idx += blockDim.x) {
        const int k = idx / TAPBLK;
        const int r = idx % TAPBLK;
        float v = 0.0f;
        if (r < 56) {
            const int q = r >> 1, half = r & 1;
            if (q < PATCH) v = w_off[(2 * k + half) * PATCH + q];
        } else if (r < 84) {
            const int i = r - 56;
            if (i < PATCH) v = w_off[(18 + k) * PATCH + i];
        } else if (r < 96) {
            const int j = r - 84;
            const int c = j >> 2, o = j & 3;
            if (o < 3) v = w_def[o * PATCH + c * KK + k];
        } else if (r < 100) {
            const int e = r - 96;
            if (e == 0)      v = b_off[2 * k];
            else if (e == 1) v = b_off[2 * k + 1];
            else if (e == 2) v = b_off[18 + k];
        }
        ws[idx] = v;
    }
}

__global__ __launch_bounds__(256) void deform_fused_kernel(
    const float* __restrict__ x,
    const float* __restrict__ wsw,    // reordered weights, 1008 floats (uniform -> SMEM)
    const float* __restrict__ b_def,
    float* __restrict__ out)
{
    const int w = blockIdx.x * blockDim.x + threadIdx.x;
    const int h = blockIdx.y;
    const int b = blockIdx.z;

    const size_t plane = (size_t)HH * WW;
    const float* xb = x + (size_t)b * CIN * plane;

    // ---- 3x3x3 zero-padded patch, flat index = c*9 + t; pad elem 27 = 0 ----
    float patch[28];
    patch[27] = 0.0f;

    const bool pint = (h >= 1) & (h < HH - 1) & (w >= 1) & (w < WW - 1);
    if (__all(pint)) {
        // interior: unclamped loads, imm-offset friendly (base at center pixel)
        const float* pc = xb + h * WW + w;
        #pragma unroll
        for (int c = 0; c < CIN; ++c) {
            const float* xp = pc + c * plane;
            #pragma unroll
            for (int d = 0; d < 3; ++d) {
                #pragma unroll
                for (int e = 0; e < 3; ++e) {
                    patch[c * KK + d * 3 + e] = xp[(d - 1) * WW + (e - 1)];
                }
            }
        }
    } else {
        #pragma unroll
        for (int c = 0; c < CIN; ++c) {
            const float* xp = xb + c * plane;
            #pragma unroll
            for (int t = 0; t < KK; ++t) {
                const int yy = h + t / 3 - 1;
                const int xx = w + t % 3 - 1;
                const bool in = ((unsigned)yy < HH) & ((unsigned)xx < WW);
                const int yc = min(max(yy, 0), HH - 1);
                const int xc = min(max(xx, 0), WW - 1);
                patch[c * KK + t] = in ? xp[yc * WW + xc] : 0.0f;
            }
        }
    }

    f2 acc01 = { b_def[0], b_def[1] };
    float acc2 = b_def[2];

    #pragma unroll 3
    for (int k = 0; k < KK; ++k) {
        const float* blk = wsw + k * TAPBLK;   // uniform address -> s_load

        const f4 bias = *(const f4*)(blk + 96);   // (boy, box, bom, 0)

        // ---- per-tap conv: (oy,ox) packed with 2-way split chain ----
        f2 oyx0 = { bias.x, bias.y };
        f2 oyx1 = { 0.0f, 0.0f };
        #pragma unroll
        for (int j = 0; j < 14; ++j) {
            const f4 wq = *(const f4*)(blk + 4 * j);
            const float p0 = patch[2 * j];
            const float p1 = patch[2 * j + 1];
            const f2 w0 = { wq.x, wq.y };
            const f2 w1 = { wq.z, wq.w };
            const f2 pp0 = { p0, p0 };
            const f2 pp1 = { p1, p1 };
            oyx0 = __builtin_elementwise_fma(w0, pp0, oyx0);
            oyx1 = __builtin_elementwise_fma(w1, pp1, oyx1);
        }
        const f2 oyx = oyx0 + oyx1;

        // ---- mask channel: 4-way split chain ----
        float om0 = bias.z, om1 = 0.0f, om2 = 0.0f, om3 = 0.0f;
        #pragma unroll
        for (int j = 0; j < 7; ++j) {
            const f4 wm4 = *(const f4*)(blk + 56 + 4 * j);
            om0 = fmaf(wm4.x, patch[4 * j],     om0);
            om1 = fmaf(wm4.y, patch[4 * j + 1], om1);
            om2 = fmaf(wm4.z, patch[4 * j + 2], om2);
            om3 = fmaf(wm4.w, patch[4 * j + 3], om3);
        }
        const float om = (om0 + om1) + (om2 + om3);

        const float m = __builtin_amdgcn_rcpf(1.0f + __expf(-om));

        const float py = (float)h + (float)(k / 3 - 1) + oyx.x;
        const float px = (float)w + (float)(k % 3 - 1) + oyx.y;
        const float y0f = floorf(py);
        const float x0f = floorf(px);
        const float dy = py - y0f;
        const float dx = px - x0f;
        const int y0 = (int)y0f;
        const int x0 = (int)x0f;

        const f2 dxp = { 1.0f - dx, dx };
        const f2 wT = dxp * (1.0f - dy);   // (w00, w01)
        const f2 wB = dxp * dy;            // (w10, w11)

        const int interior = ((unsigned)y0 < (HH - 1)) & ((unsigned)x0 < (WW - 1));

        if (__all(interior)) {
            const int idx = y0 * WW + x0;
            #pragma unroll
            for (int c = 0; c < CIN; ++c) {
                const float* xp = xb + c * plane + idx;
                const f2 vT = *(const f2u*)(xp);
                const f2 vB = *(const f2u*)(xp + WW);
                f2 s = vT * wT;
                s = __builtin_elementwise_fma(vB, wB, s);
                const float val = (s.x + s.y) * m;
                const f4 wq = *(const f4*)(blk + 84 + 4 * c);
                const f2 w01 = { wq.x, wq.y };
                const f2 vv = { val, val };
                acc01 = __builtin_elementwise_fma(w01, vv, acc01);
                acc2 = fmaf(wq.z, val, acc2);
            }
        } else {
            const bool vy0 = (unsigned)y0 < HH;
            const bool vy1 = (unsigned)(y0 + 1) < HH;
            const bool vx0 = (unsigned)x0 < WW;
            const bool vx1 = (unsigned)(x0 + 1) < WW;

            const int yc0 = min(max(y0, 0), HH - 1);
            const int yc1 = min(max(y0 + 1, 0), HH - 1);
            const int xc0 = min(max(x0, 0), WW - 1);
            const int xc1 = min(max(x0 + 1, 0), WW - 1);

            #pragma unroll
            for (int c = 0; c < CIN; ++c) {
                const float* xp = xb + c * plane;
                const float v00 = (vy0 & vx0) ? xp[yc0 * WW + xc0] : 0.0f;
                const float v01 = (vy0 & vx1) ? xp[yc0 * WW + xc1] : 0.0f;
                const float v10 = (vy1 & vx0) ? xp[yc1 * WW + xc0] : 0.0f;
                const float v11 = (vy1 & vx1) ? xp[yc1 * WW + xc1] : 0.0f;

                const float val =
                    (v00 * wT.x + v01 * wT.y + v10 * wB.x + v11 * wB.y) * m;
                const f4 wq = *(const f4*)(blk + 84 + 4 * c);
                const f2 w01 = { wq.x, wq.y };
                const f2 vv = { val, val };
                acc01 = __builtin_elementwise_fma(w01, vv, acc01);
                acc2 = fmaf(wq.z, val, acc2);
            }
        }
    }

    const size_t base = (size_t)b * (CIN * plane) + (size_t)h * WW + w;
    out[base]             = acc01.x;
    out[base + plane]     = acc01.y;
    out[base + 2 * plane] = acc2;
}

extern "C" void kernel_launch(void* const* d_in, const int* in_sizes, int n_in,
                              void* d_out, int out_size, void* d_ws, size_t ws_size,
                              hipStream_t stream) {
    const float* x     = (const float*)d_in[0];
    const float* w_off = (const float*)d_in[1];
    const float* b_off = (const float*)d_in[2];
    const float* w_def = (const float*)d_in[3];
    const float* b_def = (const float*)d_in[4];
    float* out = (float*)d_out;
    float* wsw = (float*)d_ws;   // 1008 floats of reordered weights

    reorder_weights<<<1, 256, 0, stream>>>(w_off, b_off, w_def, wsw);

    dim3 block(256, 1, 1);
    dim3 grid(WW / 256, HH, BN);  // (2, 512, 8)
    deform_fused_kernel<<<grid, block, 0, stream>>>(x, wsw, b_def, out);
}